// Round 2
// baseline (3999.401 us; speedup 1.0000x reference)
//
#include <hip/hip_runtime.h>

#define BB 16
#define NN 4096
#define NPOINTS 1024
#define KK 32
#define NPTS (BB*NPOINTS)        // 16384
#define NWN  (BB*NPOINTS*KK)     // 524288
#define EPSF 1e-5f

typedef unsigned short u16;
typedef u16  u16x8 __attribute__((ext_vector_type(8)));
typedef u16  u16x4 __attribute__((ext_vector_type(4)));
typedef float f32x4 __attribute__((ext_vector_type(4)));

__device__ __forceinline__ float bf(u16 u){
  union { unsigned int i; float f; } v; v.i = ((unsigned int)u) << 16; return v.f;
}
__device__ __forceinline__ u16 f2b(float f){
  union { float ff; unsigned int i; } v; v.ff = f;
  unsigned int r = v.i + 0x7FFFu + ((v.i >> 16) & 1u);
  return (u16)(r >> 16);
}
__device__ __forceinline__ void wave_red2(float& s, float& q){
  #pragma unroll
  for (int m = 1; m < 64; m <<= 1){ s += __shfl_xor(s, m); q += __shfl_xor(q, m); }
}

// ---------------- K0: new_xyz gather (f32 copy) ----------------
__global__ __launch_bounds__(256) void k_newxyz(const float* xyz, const int* didx, float* out){
  int p = blockIdx.x * 256 + threadIdx.x;
  if (p >= NPTS) return;
  int b = p >> 10;
  int idx = didx[p];
  const float* src = xyz + ((size_t)(b * NN + idx)) * 3;
  float* dst = out + (size_t)p * 3;
  dst[0] = src[0]; dst[1] = src[1]; dst[2] = src[2];
}

// ---------------- K2: WeightNet layer0 stats ----------------
__global__ __launch_bounds__(256) void k_wn0(const float* lc, const float* w0, const float* b0, float* S0){
  __shared__ float w0c[48], b0c[16];
  int t = threadIdx.x;
  if (t < 48) w0c[t] = w0[t];
  if (t < 16) b0c[t] = b0[t];
  __syncthreads();
  size_t p = (size_t)blockIdx.x * 256 + t;
  float x0 = lc[p*3+0], x1 = lc[p*3+1], x2 = lc[p*3+2];
  int lane = t & 63;
  #pragma unroll
  for (int oc = 0; oc < 16; ++oc){
    float y = w0c[oc*3]*x0 + w0c[oc*3+1]*x1 + w0c[oc*3+2]*x2 + b0c[oc];
    float s = y, q = y*y;
    wave_red2(s, q);
    if (lane == 0){ atomicAdd(&S0[oc], s); atomicAdd(&S0[16+oc], q); }
  }
}

// ---------------- K3: WeightNet layer1 stats ----------------
__global__ __launch_bounds__(256) void k_wn1(const float* lc, const float* w0, const float* b0,
                                             const float* g0, const float* be0, const float* S0,
                                             const float* w1, const float* b1, float* S1){
  __shared__ float w0c[48], b0c[16], a0[16], d0[16], w1c[256], b1c[16];
  int t = threadIdx.x;
  if (t < 48) w0c[t] = w0[t];
  if (t < 16){
    b0c[t] = b0[t]; b1c[t] = b1[t];
    float m = S0[t] * (1.0f/NWN);
    float v = S0[16+t] * (1.0f/NWN) - m*m;
    float a = g0[t] * rsqrtf(v + EPSF);
    a0[t] = a; d0[t] = be0[t] - m*a;
  }
  w1c[t] = w1[t];
  __syncthreads();
  size_t p = (size_t)blockIdx.x * 256 + t;
  float x0 = lc[p*3+0], x1 = lc[p*3+1], x2 = lc[p*3+2];
  float h0[16];
  #pragma unroll
  for (int oc = 0; oc < 16; ++oc){
    float y = w0c[oc*3]*x0 + w0c[oc*3+1]*x1 + w0c[oc*3+2]*x2 + b0c[oc];
    h0[oc] = fmaxf(0.f, a0[oc]*y + d0[oc]);
  }
  int lane = t & 63;
  #pragma unroll
  for (int oc = 0; oc < 16; ++oc){
    float y = b1c[oc];
    #pragma unroll
    for (int ic = 0; ic < 16; ++ic) y += w1c[oc*16+ic]*h0[ic];
    float s = y, q = y*y;
    wave_red2(s, q);
    if (lane == 0){ atomicAdd(&S1[oc], s); atomicAdd(&S1[16+oc], q); }
  }
}

// ---------------- K4: WeightNet layer2 stats ----------------
__global__ __launch_bounds__(256) void k_wn2(const float* lc,
    const float* w0, const float* b0, const float* g0, const float* be0, const float* S0,
    const float* w1, const float* b1, const float* g1, const float* be1, const float* S1,
    const float* w2, const float* b2, float* S2){
  __shared__ float w0c[48], b0c[16], a0[16], d0[16];
  __shared__ float w1c[256], b1c[16], a1[16], d1[16];
  __shared__ float w2c[1024], b2c[64];
  __shared__ float shS[64], shQ[64];
  int t = threadIdx.x;
  if (t < 48) w0c[t] = w0[t];
  if (t < 16){
    b0c[t] = b0[t]; b1c[t] = b1[t];
    float m = S0[t] * (1.0f/NWN);
    float v = S0[16+t] * (1.0f/NWN) - m*m;
    float a = g0[t] * rsqrtf(v + EPSF);
    a0[t] = a; d0[t] = be0[t] - m*a;
    float m1 = S1[t] * (1.0f/NWN);
    float v1 = S1[16+t] * (1.0f/NWN) - m1*m1;
    float aa = g1[t] * rsqrtf(v1 + EPSF);
    a1[t] = aa; d1[t] = be1[t] - m1*aa;
  }
  w1c[t] = w1[t];
  for (int i = t; i < 1024; i += 256) w2c[i] = w2[i];
  if (t < 64){ b2c[t] = b2[t]; shS[t] = 0.f; shQ[t] = 0.f; }
  __syncthreads();
  size_t p = (size_t)blockIdx.x * 256 + t;
  float x0 = lc[p*3+0], x1 = lc[p*3+1], x2 = lc[p*3+2];
  float h0[16], h1[16];
  #pragma unroll
  for (int oc = 0; oc < 16; ++oc){
    float y = w0c[oc*3]*x0 + w0c[oc*3+1]*x1 + w0c[oc*3+2]*x2 + b0c[oc];
    h0[oc] = fmaxf(0.f, a0[oc]*y + d0[oc]);
  }
  #pragma unroll
  for (int oc = 0; oc < 16; ++oc){
    float y = b1c[oc];
    #pragma unroll
    for (int ic = 0; ic < 16; ++ic) y += w1c[oc*16+ic]*h0[ic];
    h1[oc] = fmaxf(0.f, a1[oc]*y + d1[oc]);
  }
  int lane = t & 63;
  for (int oc = 0; oc < 64; ++oc){
    float y = b2c[oc];
    #pragma unroll
    for (int ic = 0; ic < 16; ++ic) y += w2c[oc*16+ic]*h1[ic];
    float s = y, q = y*y;
    wave_red2(s, q);
    if (lane == 0){ atomicAdd(&shS[oc], s); atomicAdd(&shQ[oc], q); }
  }
  __syncthreads();
  if (t < 64){ atomicAdd(&S2[t], shS[t]); atomicAdd(&S2[64+t], shQ[t]); }
}

// ---------------- K5: main pass — gather + WeightNet + per-point 64x32x64 matmul ----------------
__global__ __launch_bounds__(256) void k_main(const float* lcg, const int* nbrg,
    const float* points, const float* xyz,
    const float* w0, const float* b0, const float* g0, const float* be0, const float* S0,
    const float* w1, const float* b1, const float* g1, const float* be1, const float* S1,
    const float* w2, const float* b2, const float* g2, const float* be2, const float* S2,
    u16* npw, float* statsC){
  __shared__ float G[32][64];
  __shared__ float W[32][64];
  __shared__ float H0[32][16];
  __shared__ float H1[32][16];
  __shared__ float lcs[32][4];
  __shared__ int   nbr[32];
  __shared__ float w0c[48], b0c[16], a0c[16], d0c[16];
  __shared__ float w1c[16][17], b1c[16], a1c[16], d1c[16];
  __shared__ float w2c[64][17], b2c[64], a2c[64], d2c[64];
  int t = threadIdx.x;
  if (t < 48) w0c[t] = w0[t];
  if (t < 16){
    b0c[t] = b0[t]; b1c[t] = b1[t];
    float m = S0[t] * (1.0f/NWN);
    float v = S0[16+t] * (1.0f/NWN) - m*m;
    float a = g0[t] * rsqrtf(v + EPSF);
    a0c[t] = a; d0c[t] = be0[t] - m*a;
    float m1 = S1[t] * (1.0f/NWN);
    float v1 = S1[16+t] * (1.0f/NWN) - m1*m1;
    float aa = g1[t] * rsqrtf(v1 + EPSF);
    a1c[t] = aa; d1c[t] = be1[t] - m1*aa;
  }
  w1c[t>>4][t&15] = w1[t];
  for (int i = t; i < 1024; i += 256) w2c[i>>4][i&15] = w2[i];
  if (t < 64){
    b2c[t] = b2[t];
    float m = S2[t] * (1.0f/NWN);
    float v = S2[64+t] * (1.0f/NWN) - m*m;
    float a = g2[t] * rsqrtf(v + EPSF);
    a2c[t] = a; d2c[t] = be2[t] - m*a;
  }
  int ti = t & 15, to = t >> 4;
  int i0 = ti * 4, o0 = to * 4;
  f32x4 cs0 = {0,0,0,0}, cs1 = cs0, cs2 = cs0, cs3 = cs0;
  f32x4 cq0 = cs0, cq1 = cs0, cq2 = cs0, cq3 = cs0;
  for (int p = 0; p < 16; ++p){
    int point = blockIdx.x * 16 + p;
    int b = point >> 10;
    __syncthreads();  // previous matmul done before overwriting LDS
    if (t < 32) nbr[t] = nbrg[(size_t)point * 32 + t];
    if (t < 96){ int k = t / 3, c = t % 3; lcs[k][c] = lcg[(size_t)point * 96 + t]; }
    __syncthreads();
    // gather grouped [32 nbr][64 ch] directly from points/xyz
    {
      int k = t >> 3, c8 = t & 7;
      int n = nbr[k];
      const float* prow = points + (size_t)(b * NN + n) * 61;
      const float* xr   = xyz    + (size_t)(b * NN + n) * 3;
      #pragma unroll
      for (int j = 0; j < 8; ++j){
        int c = c8 * 8 + j;
        G[k][c] = (c < 61) ? prow[c] : xr[c - 61];
      }
    }
    #pragma unroll
    for (int j = 0; j < 2; ++j){
      int l = t + j * 256; int k = l >> 4, oc = l & 15;
      float y = w0c[oc*3]*lcs[k][0] + w0c[oc*3+1]*lcs[k][1] + w0c[oc*3+2]*lcs[k][2] + b0c[oc];
      H0[k][oc] = fmaxf(0.f, a0c[oc]*y + d0c[oc]);
    }
    __syncthreads();
    #pragma unroll
    for (int j = 0; j < 2; ++j){
      int l = t + j * 256; int k = l >> 4, oc = l & 15;
      float y = b1c[oc];
      #pragma unroll
      for (int ic = 0; ic < 16; ++ic) y += w1c[oc][ic] * H0[k][ic];
      H1[k][oc] = fmaxf(0.f, a1c[oc]*y + d1c[oc]);
    }
    __syncthreads();
    {
      int oo = t & 63;
      #pragma unroll
      for (int e = 0; e < 8; ++e){
        int k = (t >> 6) + e * 4;
        float y = b2c[oo];
        #pragma unroll
        for (int ic = 0; ic < 16; ++ic) y += w2c[oo][ic] * H1[k][ic];
        W[k][oo] = fmaxf(0.f, a2c[oo]*y + d2c[oo]);
      }
    }
    __syncthreads();
    // matmul: np[i][o] = sum_k G[k][i]*W[k][o], 4x4 register tile
    f32x4 acc0 = {0,0,0,0}, acc1 = acc0, acc2 = acc0, acc3 = acc0;
    #pragma unroll
    for (int k = 0; k < 32; ++k){
      f32x4 g = *(const f32x4*)&G[k][i0];
      f32x4 w = *(const f32x4*)&W[k][o0];
      acc0 += g.x * w; acc1 += g.y * w; acc2 += g.z * w; acc3 += g.w * w;
    }
    size_t rowb = (size_t)point * 4096 + o0;
    u16x4 u;
    u[0]=f2b(acc0.x); u[1]=f2b(acc0.y); u[2]=f2b(acc0.z); u[3]=f2b(acc0.w);
    *(u16x4*)(npw + rowb + (size_t)(i0+0)*64) = u;
    u[0]=f2b(acc1.x); u[1]=f2b(acc1.y); u[2]=f2b(acc1.z); u[3]=f2b(acc1.w);
    *(u16x4*)(npw + rowb + (size_t)(i0+1)*64) = u;
    u[0]=f2b(acc2.x); u[1]=f2b(acc2.y); u[2]=f2b(acc2.z); u[3]=f2b(acc2.w);
    *(u16x4*)(npw + rowb + (size_t)(i0+2)*64) = u;
    u[0]=f2b(acc3.x); u[1]=f2b(acc3.y); u[2]=f2b(acc3.z); u[3]=f2b(acc3.w);
    *(u16x4*)(npw + rowb + (size_t)(i0+3)*64) = u;
    cs0 += acc0; cq0 += acc0*acc0;
    cs1 += acc1; cq1 += acc1*acc1;
    cs2 += acc2; cq2 += acc2*acc2;
    cs3 += acc3; cq3 += acc3*acc3;
  }
  // each thread owns 16 distinct channels: (i0+di)*64 + (o0+dj)
  int ch0 = i0 * 64 + o0;
  #pragma unroll
  for (int dj = 0; dj < 4; ++dj){
    atomicAdd(&statsC[ch0 +   0 + dj], cs0[dj]); atomicAdd(&statsC[4096 + ch0 +   0 + dj], cq0[dj]);
    atomicAdd(&statsC[ch0 +  64 + dj], cs1[dj]); atomicAdd(&statsC[4096 + ch0 +  64 + dj], cq1[dj]);
    atomicAdd(&statsC[ch0 + 128 + dj], cs2[dj]); atomicAdd(&statsC[4096 + ch0 + 128 + dj], cq2[dj]);
    atomicAdd(&statsC[ch0 + 192 + dj], cs3[dj]); atomicAdd(&statsC[4096 + ch0 + 192 + dj], cq3[dj]);
  }
}

// ---------------- K6b: finalize 4096-channel BN scale/shift ----------------
__global__ __launch_bounds__(256) void k_finC(const float* statsC, const float* gc, const float* bc,
                                              float* AC, float* DC){
  int ch = blockIdx.x * 256 + threadIdx.x;
  float m = statsC[ch] * (1.f/16384.f);
  float v = statsC[4096 + ch] * (1.f/16384.f) - m*m;
  float a = gc[ch] * rsqrtf(v + EPSF);
  AC[ch] = a; DC[ch] = bc[ch] - m*a;
}

// ---------------- K7: [16384,4096] x [4096,64] with fused bn+relu on A ----------------
__global__ __launch_bounds__(256) void k_linear(const u16* npw, const float* AC, const float* DC,
                                                const float* lw, const float* lb, float* yw){
  __shared__ float npt[64][65];
  __shared__ float lwt[64][64];
  int t = threadIdx.x;
  int rowbase = blockIdx.x * 64;
  int r0 = (t & 31) * 2;
  int o0 = (t >> 5) * 8;
  f32x4 accA = {0,0,0,0}, accB = accA, accC = accA, accD = accA;
  for (int cb = 0; cb < 64; ++cb){
    __syncthreads();
    #pragma unroll
    for (int j = 0; j < 2; ++j){
      int l = t + j * 256; int rr = l >> 3, c8 = l & 7;
      int cbase = cb * 64 + c8 * 8;
      u16x8 u = *(const u16x8*)(npw + (size_t)(rowbase + rr) * 4096 + cbase);
      f32x4 alo = *(const f32x4*)(AC + cbase);
      f32x4 ahi = *(const f32x4*)(AC + cbase + 4);
      f32x4 dlo = *(const f32x4*)(DC + cbase);
      f32x4 dhi = *(const f32x4*)(DC + cbase + 4);
      npt[rr][c8*8+0] = fmaxf(0.f, alo.x*bf(u[0]) + dlo.x);
      npt[rr][c8*8+1] = fmaxf(0.f, alo.y*bf(u[1]) + dlo.y);
      npt[rr][c8*8+2] = fmaxf(0.f, alo.z*bf(u[2]) + dlo.z);
      npt[rr][c8*8+3] = fmaxf(0.f, alo.w*bf(u[3]) + dlo.w);
      npt[rr][c8*8+4] = fmaxf(0.f, ahi.x*bf(u[4]) + dhi.x);
      npt[rr][c8*8+5] = fmaxf(0.f, ahi.y*bf(u[5]) + dhi.y);
      npt[rr][c8*8+6] = fmaxf(0.f, ahi.z*bf(u[6]) + dhi.z);
      npt[rr][c8*8+7] = fmaxf(0.f, ahi.w*bf(u[7]) + dhi.w);
    }
    #pragma unroll
    for (int j = 0; j < 2; ++j){
      int l = t + j * 256; int cc = l >> 3, o8 = l & 7;
      const float* src = lw + (size_t)(cb * 64 + cc) * 64 + o8 * 8;
      *(f32x4*)&lwt[cc][o8*8]     = *(const f32x4*)src;
      *(f32x4*)&lwt[cc][o8*8 + 4] = *(const f32x4*)(src + 4);
    }
    __syncthreads();
    #pragma unroll 8
    for (int cc = 0; cc < 64; ++cc){
      float x0 = npt[r0][cc], x1 = npt[r0+1][cc];
      f32x4 wA = *(const f32x4*)&lwt[cc][o0];
      f32x4 wB = *(const f32x4*)&lwt[cc][o0+4];
      accA += x0 * wA; accB += x0 * wB;
      accC += x1 * wA; accD += x1 * wB;
    }
  }
  f32x4 lbA = *(const f32x4*)(lb + o0);
  f32x4 lbB = *(const f32x4*)(lb + o0 + 4);
  accA += lbA; accB += lbB; accC += lbA; accD += lbB;
  float* dst0 = yw + (size_t)(rowbase + r0) * 64 + o0;
  *(f32x4*)dst0 = accA; *(f32x4*)(dst0 + 4) = accB;
  float* dst1 = yw + (size_t)(rowbase + r0 + 1) * 64 + o0;
  *(f32x4*)dst1 = accC; *(f32x4*)(dst1 + 4) = accD;
}

// ---------------- K8a: final-BN stats ----------------
__global__ __launch_bounds__(256) void k_statL(const float* yw, float* SL){
  int t = threadIdx.x;
  int o = t & 63;
  int rg = blockIdx.x * 4 + (t >> 6);
  float s = 0.f, q = 0.f;
  for (int r = rg * 64; r < rg * 64 + 64; ++r){
    float v = yw[(size_t)r * 64 + o];
    s += v; q += v*v;
  }
  atomicAdd(&SL[o], s);
  atomicAdd(&SL[64 + o], q);
}

// ---------------- K8b: final bn + relu + f32 store ----------------
__global__ __launch_bounds__(256) void k_final(const float* yw, const float* SL,
                                               const float* gl, const float* bl, float* out){
  int gid = blockIdx.x * 256 + threadIdx.x;  // < 16384*64
  int o = gid & 63;
  float m = SL[o] * (1.f/16384.f);
  float v = SL[64 + o] * (1.f/16384.f) - m*m;
  float a = gl[o] * rsqrtf(v + EPSF);
  float d = bl[o] - m*a;
  float y = fmaxf(0.f, a * yw[gid] + d);
  out[49152 + gid] = y;
}

extern "C" void kernel_launch(void* const* d_in, const int* in_sizes, int n_in,
                              void* d_out, int out_size, void* d_ws, size_t ws_size,
                              hipStream_t stream){
  (void)in_sizes; (void)n_in; (void)out_size; (void)ws_size;
  const float* xyz    = (const float*)d_in[0];
  const float* points = (const float*)d_in[1];
  const float* lc     = (const float*)d_in[2];
  const int*   nbrl   = (const int*)d_in[3];
  const int*   didx   = (const int*)d_in[4];
  const float* w0 = (const float*)d_in[5];
  const float* b0 = (const float*)d_in[6];
  const float* g0 = (const float*)d_in[7];
  const float* be0= (const float*)d_in[8];
  const float* w1 = (const float*)d_in[9];
  const float* b1 = (const float*)d_in[10];
  const float* g1 = (const float*)d_in[11];
  const float* be1= (const float*)d_in[12];
  const float* w2 = (const float*)d_in[13];
  const float* b2 = (const float*)d_in[14];
  const float* g2 = (const float*)d_in[15];
  const float* be2= (const float*)d_in[16];
  const float* gc = (const float*)d_in[17];
  const float* bc = (const float*)d_in[18];
  const float* lw = (const float*)d_in[19];
  const float* lb = (const float*)d_in[20];
  const float* gl = (const float*)d_in[21];
  const float* bl = (const float*)d_in[22];
  float* out = (float*)d_out;
  char* ws = (char*)d_ws;

  // float-offset layout in ws:
  float* S0 = (float*)ws;          // 32   @0
  float* S1 = S0 + 32;             // 32   @32
  float* S2 = S1 + 32;             // 128  @64
  float* SL = S2 + 128;            // 128  @192
  float* statsC = SL + 128;        // 8192 @320
  float* AC = statsC + 8192;       // 4096 @8512
  float* DC = AC + 4096;           // 4096 @12608  (end 16704 floats = 66816 B)
  u16*  npw = (u16*)(ws + 131072);                       // 128 MB bf16
  float* yw = (float*)(ws + 131072 + 134217728);         // 4 MB f32

  hipMemsetAsync(d_ws, 0, 36864, stream);   // zeros S0,S1,S2,SL,statsC
  k_newxyz <<<64,   256, 0, stream>>>(xyz, didx, out);
  k_wn0    <<<2048, 256, 0, stream>>>(lc, w0, b0, S0);
  k_wn1    <<<2048, 256, 0, stream>>>(lc, w0, b0, g0, be0, S0, w1, b1, S1);
  k_wn2    <<<2048, 256, 0, stream>>>(lc, w0, b0, g0, be0, S0, w1, b1, g1, be1, S1, w2, b2, S2);
  k_main   <<<1024, 256, 0, stream>>>(lc, nbrl, points, xyz,
                                      w0, b0, g0, be0, S0,
                                      w1, b1, g1, be1, S1,
                                      w2, b2, g2, be2, S2,
                                      npw, statsC);
  k_finC   <<<16,   256, 0, stream>>>(statsC, gc, bc, AC, DC);
  k_linear <<<256,  256, 0, stream>>>(npw, AC, DC, lw, lb, yw);
  k_statL  <<<64,   256, 0, stream>>>(yw, SL);
  k_final  <<<4096, 256, 0, stream>>>(yw, SL, gl, bl, out);
}

// Round 3
// 2040.778 us; speedup vs baseline: 1.9597x; 1.9597x over previous
//
#include <hip/hip_runtime.h>

#define BB 16
#define NN 4096
#define NPOINTS 1024
#define KK 32
#define NPTS (BB*NPOINTS)        // 16384
#define NWN  (BB*NPOINTS*KK)     // 524288
#define EPSF 1e-5f
#define NSLOT 16

typedef unsigned short u16;
typedef u16  u16x8 __attribute__((ext_vector_type(8)));
typedef u16  u16x4 __attribute__((ext_vector_type(4)));
typedef float f32x4 __attribute__((ext_vector_type(4)));

__device__ __forceinline__ float bf(u16 u){
  union { unsigned int i; float f; } v; v.i = ((unsigned int)u) << 16; return v.f;
}
__device__ __forceinline__ u16 f2b(float f){
  union { float ff; unsigned int i; } v; v.ff = f;
  unsigned int r = v.i + 0x7FFFu + ((v.i >> 16) & 1u);
  return (u16)(r >> 16);
}
__device__ __forceinline__ void wave_red2(float& s, float& q){
  #pragma unroll
  for (int m = 1; m < 64; m <<= 1){ s += __shfl_xor(s, m); q += __shfl_xor(q, m); }
}

// ---------------- K0: new_xyz gather (f32 copy) ----------------
__global__ __launch_bounds__(256) void k_newxyz(const float* xyz, const int* didx, float* out){
  int p = blockIdx.x * 256 + threadIdx.x;
  if (p >= NPTS) return;
  int b = p >> 10;
  int idx = didx[p];
  const float* src = xyz + ((size_t)(b * NN + idx)) * 3;
  float* dst = out + (size_t)p * 3;
  dst[0] = src[0]; dst[1] = src[1]; dst[2] = src[2];
}

// ---------------- stats kernels: 256 blocks, 8 points/thread, partial write (no atomics) ----------------
__global__ __launch_bounds__(256) void k_wn0(const float* lc, const float* w0, const float* b0, float* P0){
  __shared__ float w0c[48], b0c[16];
  __shared__ float shs[4][16], shq[4][16];
  int t = threadIdx.x;
  if (t < 48) w0c[t] = w0[t];
  if (t < 16) b0c[t] = b0[t];
  __syncthreads();
  float s[16], q[16];
  #pragma unroll
  for (int oc = 0; oc < 16; ++oc){ s[oc] = 0.f; q[oc] = 0.f; }
  size_t base = (size_t)blockIdx.x * 2048 + t;
  for (int i = 0; i < 8; ++i){
    size_t p = base + (size_t)i * 256;
    float x0 = lc[p*3+0], x1 = lc[p*3+1], x2 = lc[p*3+2];
    #pragma unroll
    for (int oc = 0; oc < 16; ++oc){
      float y = w0c[oc*3]*x0 + w0c[oc*3+1]*x1 + w0c[oc*3+2]*x2 + b0c[oc];
      s[oc] += y; q[oc] += y*y;
    }
  }
  int lane = t & 63, wid = t >> 6;
  #pragma unroll
  for (int oc = 0; oc < 16; ++oc){
    wave_red2(s[oc], q[oc]);
    if (lane == 0){ shs[wid][oc] = s[oc]; shq[wid][oc] = q[oc]; }
  }
  __syncthreads();
  if (t < 16){
    P0[blockIdx.x*32 + t]      = shs[0][t] + shs[1][t] + shs[2][t] + shs[3][t];
    P0[blockIdx.x*32 + 16 + t] = shq[0][t] + shq[1][t] + shq[2][t] + shq[3][t];
  }
}

__global__ __launch_bounds__(256) void k_wn1(const float* lc, const float* w0, const float* b0,
                                             const float* g0, const float* be0, const float* S0,
                                             const float* w1, const float* b1, float* P1){
  __shared__ float w0c[48], b0c[16], a0[16], d0[16], w1c[256], b1c[16];
  __shared__ float shs[4][16], shq[4][16];
  int t = threadIdx.x;
  if (t < 48) w0c[t] = w0[t];
  if (t < 16){
    b0c[t] = b0[t]; b1c[t] = b1[t];
    float m = S0[t] * (1.0f/NWN);
    float v = S0[16+t] * (1.0f/NWN) - m*m;
    float a = g0[t] * rsqrtf(v + EPSF);
    a0[t] = a; d0[t] = be0[t] - m*a;
  }
  w1c[t] = w1[t];
  __syncthreads();
  float s[16], q[16];
  #pragma unroll
  for (int oc = 0; oc < 16; ++oc){ s[oc] = 0.f; q[oc] = 0.f; }
  size_t base = (size_t)blockIdx.x * 2048 + t;
  for (int i = 0; i < 8; ++i){
    size_t p = base + (size_t)i * 256;
    float x0 = lc[p*3+0], x1 = lc[p*3+1], x2 = lc[p*3+2];
    float h0[16];
    #pragma unroll
    for (int oc = 0; oc < 16; ++oc){
      float y = w0c[oc*3]*x0 + w0c[oc*3+1]*x1 + w0c[oc*3+2]*x2 + b0c[oc];
      h0[oc] = fmaxf(0.f, a0[oc]*y + d0[oc]);
    }
    #pragma unroll
    for (int oc = 0; oc < 16; ++oc){
      float y = b1c[oc];
      #pragma unroll
      for (int ic = 0; ic < 16; ++ic) y += w1c[oc*16+ic]*h0[ic];
      s[oc] += y; q[oc] += y*y;
    }
  }
  int lane = t & 63, wid = t >> 6;
  #pragma unroll
  for (int oc = 0; oc < 16; ++oc){
    wave_red2(s[oc], q[oc]);
    if (lane == 0){ shs[wid][oc] = s[oc]; shq[wid][oc] = q[oc]; }
  }
  __syncthreads();
  if (t < 16){
    P1[blockIdx.x*32 + t]      = shs[0][t] + shs[1][t] + shs[2][t] + shs[3][t];
    P1[blockIdx.x*32 + 16 + t] = shq[0][t] + shq[1][t] + shq[2][t] + shq[3][t];
  }
}

__global__ __launch_bounds__(256) void k_wn2(const float* lc,
    const float* w0, const float* b0, const float* g0, const float* be0, const float* S0,
    const float* w1, const float* b1, const float* g1, const float* be1, const float* S1,
    const float* w2, const float* b2, float* P2){
  __shared__ float w0c[48], b0c[16], a0[16], d0[16];
  __shared__ float w1c[256], b1c[16], a1[16], d1[16];
  __shared__ float w2c[1024], b2c[64];
  __shared__ float shs[4][64], shq[4][64];
  int t = threadIdx.x;
  if (t < 48) w0c[t] = w0[t];
  if (t < 16){
    b0c[t] = b0[t]; b1c[t] = b1[t];
    float m = S0[t] * (1.0f/NWN);
    float v = S0[16+t] * (1.0f/NWN) - m*m;
    float a = g0[t] * rsqrtf(v + EPSF);
    a0[t] = a; d0[t] = be0[t] - m*a;
    float m1 = S1[t] * (1.0f/NWN);
    float v1 = S1[16+t] * (1.0f/NWN) - m1*m1;
    float aa = g1[t] * rsqrtf(v1 + EPSF);
    a1[t] = aa; d1[t] = be1[t] - m1*aa;
  }
  w1c[t] = w1[t];
  for (int i = t; i < 1024; i += 256) w2c[i] = w2[i];
  if (t < 64) b2c[t] = b2[t];
  __syncthreads();
  float s2[32], q2[32];   // ocs split: this thread handles all 64 but accumulate in 2 halves to cap VGPR
  float s3[32], q3[32];
  #pragma unroll
  for (int oc = 0; oc < 32; ++oc){ s2[oc]=0.f; q2[oc]=0.f; s3[oc]=0.f; q3[oc]=0.f; }
  size_t base = (size_t)blockIdx.x * 2048 + t;
  for (int i = 0; i < 8; ++i){
    size_t p = base + (size_t)i * 256;
    float x0 = lc[p*3+0], x1 = lc[p*3+1], x2 = lc[p*3+2];
    float h0[16], h1[16];
    #pragma unroll
    for (int oc = 0; oc < 16; ++oc){
      float y = w0c[oc*3]*x0 + w0c[oc*3+1]*x1 + w0c[oc*3+2]*x2 + b0c[oc];
      h0[oc] = fmaxf(0.f, a0[oc]*y + d0[oc]);
    }
    #pragma unroll
    for (int oc = 0; oc < 16; ++oc){
      float y = b1c[oc];
      #pragma unroll
      for (int ic = 0; ic < 16; ++ic) y += w1c[oc*16+ic]*h0[ic];
      h1[oc] = fmaxf(0.f, a1[oc]*y + d1[oc]);
    }
    #pragma unroll
    for (int oc = 0; oc < 32; ++oc){
      float y = b2c[oc];
      #pragma unroll
      for (int ic = 0; ic < 16; ++ic) y += w2c[oc*16+ic]*h1[ic];
      s2[oc] += y; q2[oc] += y*y;
    }
    #pragma unroll
    for (int oc = 0; oc < 32; ++oc){
      float y = b2c[32+oc];
      #pragma unroll
      for (int ic = 0; ic < 16; ++ic) y += w2c[(32+oc)*16+ic]*h1[ic];
      s3[oc] += y; q3[oc] += y*y;
    }
  }
  int lane = t & 63, wid = t >> 6;
  #pragma unroll
  for (int oc = 0; oc < 32; ++oc){
    wave_red2(s2[oc], q2[oc]);
    if (lane == 0){ shs[wid][oc] = s2[oc]; shq[wid][oc] = q2[oc]; }
  }
  #pragma unroll
  for (int oc = 0; oc < 32; ++oc){
    wave_red2(s3[oc], q3[oc]);
    if (lane == 0){ shs[wid][32+oc] = s3[oc]; shq[wid][32+oc] = q3[oc]; }
  }
  __syncthreads();
  if (t < 64){
    P2[blockIdx.x*128 + t]      = shs[0][t] + shs[1][t] + shs[2][t] + shs[3][t];
    P2[blockIdx.x*128 + 64 + t] = shq[0][t] + shq[1][t] + shq[2][t] + shq[3][t];
  }
}

// ---------------- generic partial reduce: S[c] = sum over 256 rows of P[r*nch + c] ----------------
__global__ __launch_bounds__(256) void k_redP(const float* P, float* S, int nch){
  int t = threadIdx.x;
  if (t >= nch) return;
  float s = 0.f;
  for (int r = 0; r < 256; ++r) s += P[r*nch + t];
  S[t] = s;
}

// ---------------- K5: main pass — gather + WeightNet + per-point 64x32x64 matmul ----------------
__global__ __launch_bounds__(256) void k_main(const float* lcg, const int* nbrg,
    const float* points, const float* xyz,
    const float* w0, const float* b0, const float* g0, const float* be0, const float* S0,
    const float* w1, const float* b1, const float* g1, const float* be1, const float* S1,
    const float* w2, const float* b2, const float* g2, const float* be2, const float* S2,
    u16* npw, float* slotC){
  __shared__ float G[32][64];
  __shared__ float W[32][64];
  __shared__ float H0[32][16];
  __shared__ float H1[32][16];
  __shared__ float lcs[32][4];
  __shared__ int   nbr[32];
  __shared__ float w0c[48], b0c[16], a0c[16], d0c[16];
  __shared__ float w1c[16][17], b1c[16], a1c[16], d1c[16];
  __shared__ float w2c[64][17], b2c[64], a2c[64], d2c[64];
  int t = threadIdx.x;
  if (t < 48) w0c[t] = w0[t];
  if (t < 16){
    b0c[t] = b0[t]; b1c[t] = b1[t];
    float m = S0[t] * (1.0f/NWN);
    float v = S0[16+t] * (1.0f/NWN) - m*m;
    float a = g0[t] * rsqrtf(v + EPSF);
    a0c[t] = a; d0c[t] = be0[t] - m*a;
    float m1 = S1[t] * (1.0f/NWN);
    float v1 = S1[16+t] * (1.0f/NWN) - m1*m1;
    float aa = g1[t] * rsqrtf(v1 + EPSF);
    a1c[t] = aa; d1c[t] = be1[t] - m1*aa;
  }
  w1c[t>>4][t&15] = w1[t];
  for (int i = t; i < 1024; i += 256) w2c[i>>4][i&15] = w2[i];
  if (t < 64){
    b2c[t] = b2[t];
    float m = S2[t] * (1.0f/NWN);
    float v = S2[64+t] * (1.0f/NWN) - m*m;
    float a = g2[t] * rsqrtf(v + EPSF);
    a2c[t] = a; d2c[t] = be2[t] - m*a;
  }
  int ti = t & 15, to = t >> 4;
  int i0 = ti * 4, o0 = to * 4;
  f32x4 cs0 = {0,0,0,0}, cs1 = cs0, cs2 = cs0, cs3 = cs0;
  f32x4 cq0 = cs0, cq1 = cs0, cq2 = cs0, cq3 = cs0;
  for (int p = 0; p < 16; ++p){
    int point = blockIdx.x * 16 + p;
    int b = point >> 10;
    __syncthreads();  // previous matmul done before overwriting LDS
    if (t < 32) nbr[t] = nbrg[(size_t)point * 32 + t];
    if (t < 96){ int k = t / 3, c = t % 3; lcs[k][c] = lcg[(size_t)point * 96 + t]; }
    __syncthreads();
    // gather grouped [32 nbr][64 ch] directly from points/xyz
    {
      int k = t >> 3, c8 = t & 7;
      int n = nbr[k];
      const float* prow = points + (size_t)(b * NN + n) * 61;
      const float* xr   = xyz    + (size_t)(b * NN + n) * 3;
      #pragma unroll
      for (int j = 0; j < 8; ++j){
        int c = c8 * 8 + j;
        G[k][c] = (c < 61) ? prow[c] : xr[c - 61];
      }
    }
    #pragma unroll
    for (int j = 0; j < 2; ++j){
      int l = t + j * 256; int k = l >> 4, oc = l & 15;
      float y = w0c[oc*3]*lcs[k][0] + w0c[oc*3+1]*lcs[k][1] + w0c[oc*3+2]*lcs[k][2] + b0c[oc];
      H0[k][oc] = fmaxf(0.f, a0c[oc]*y + d0c[oc]);
    }
    __syncthreads();
    #pragma unroll
    for (int j = 0; j < 2; ++j){
      int l = t + j * 256; int k = l >> 4, oc = l & 15;
      float y = b1c[oc];
      #pragma unroll
      for (int ic = 0; ic < 16; ++ic) y += w1c[oc][ic] * H0[k][ic];
      H1[k][oc] = fmaxf(0.f, a1c[oc]*y + d1c[oc]);
    }
    __syncthreads();
    {
      int oo = t & 63;
      #pragma unroll
      for (int e = 0; e < 8; ++e){
        int k = (t >> 6) + e * 4;
        float y = b2c[oo];
        #pragma unroll
        for (int ic = 0; ic < 16; ++ic) y += w2c[oo][ic] * H1[k][ic];
        W[k][oo] = fmaxf(0.f, a2c[oo]*y + d2c[oo]);
      }
    }
    __syncthreads();
    // matmul: np[i][o] = sum_k G[k][i]*W[k][o], 4x4 register tile
    f32x4 acc0 = {0,0,0,0}, acc1 = acc0, acc2 = acc0, acc3 = acc0;
    #pragma unroll
    for (int k = 0; k < 32; ++k){
      f32x4 g = *(const f32x4*)&G[k][i0];
      f32x4 w = *(const f32x4*)&W[k][o0];
      acc0 += g.x * w; acc1 += g.y * w; acc2 += g.z * w; acc3 += g.w * w;
    }
    size_t rowb = (size_t)point * 4096 + o0;
    u16x4 u;
    u[0]=f2b(acc0.x); u[1]=f2b(acc0.y); u[2]=f2b(acc0.z); u[3]=f2b(acc0.w);
    *(u16x4*)(npw + rowb + (size_t)(i0+0)*64) = u;
    u[0]=f2b(acc1.x); u[1]=f2b(acc1.y); u[2]=f2b(acc1.z); u[3]=f2b(acc1.w);
    *(u16x4*)(npw + rowb + (size_t)(i0+1)*64) = u;
    u[0]=f2b(acc2.x); u[1]=f2b(acc2.y); u[2]=f2b(acc2.z); u[3]=f2b(acc2.w);
    *(u16x4*)(npw + rowb + (size_t)(i0+2)*64) = u;
    u[0]=f2b(acc3.x); u[1]=f2b(acc3.y); u[2]=f2b(acc3.z); u[3]=f2b(acc3.w);
    *(u16x4*)(npw + rowb + (size_t)(i0+3)*64) = u;
    cs0 += acc0; cq0 += acc0*acc0;
    cs1 += acc1; cq1 += acc1*acc1;
    cs2 += acc2; cq2 += acc2*acc2;
    cs3 += acc3; cq3 += acc3*acc3;
  }
  // channel sums -> one of NSLOT slot copies (cuts same-address chains NSLOT-fold)
  float* slot = slotC + (size_t)(blockIdx.x & (NSLOT-1)) * 8192;
  int ch0 = i0 * 64 + o0;
  #pragma unroll
  for (int dj = 0; dj < 4; ++dj){
    atomicAdd(&slot[ch0 +   0 + dj], cs0[dj]); atomicAdd(&slot[4096 + ch0 +   0 + dj], cq0[dj]);
    atomicAdd(&slot[ch0 +  64 + dj], cs1[dj]); atomicAdd(&slot[4096 + ch0 +  64 + dj], cq1[dj]);
    atomicAdd(&slot[ch0 + 128 + dj], cs2[dj]); atomicAdd(&slot[4096 + ch0 + 128 + dj], cq2[dj]);
    atomicAdd(&slot[ch0 + 192 + dj], cs3[dj]); atomicAdd(&slot[4096 + ch0 + 192 + dj], cq3[dj]);
  }
}

// ---------------- K6b: reduce slots + finalize 4096-channel BN scale/shift ----------------
__global__ __launch_bounds__(256) void k_finC(const float* slotC, const float* gc, const float* bc,
                                              float* AC, float* DC){
  int ch = blockIdx.x * 256 + threadIdx.x;
  float s = 0.f, q = 0.f;
  #pragma unroll
  for (int sl = 0; sl < NSLOT; ++sl){
    s += slotC[(size_t)sl * 8192 + ch];
    q += slotC[(size_t)sl * 8192 + 4096 + ch];
  }
  float m = s * (1.f/16384.f);
  float v = q * (1.f/16384.f) - m*m;
  float a = gc[ch] * rsqrtf(v + EPSF);
  AC[ch] = a; DC[ch] = bc[ch] - m*a;
}

// ---------------- K7: [16384,4096] x [4096,64] with fused bn+relu on A ----------------
__global__ __launch_bounds__(256) void k_linear(const u16* npw, const float* AC, const float* DC,
                                                const float* lw, const float* lb, float* yw){
  __shared__ float npt[64][65];
  __shared__ float lwt[64][64];
  int t = threadIdx.x;
  int rowbase = blockIdx.x * 64;
  int r0 = (t & 31) * 2;
  int o0 = (t >> 5) * 8;
  f32x4 accA = {0,0,0,0}, accB = accA, accC = accA, accD = accA;
  for (int cb = 0; cb < 64; ++cb){
    __syncthreads();
    #pragma unroll
    for (int j = 0; j < 2; ++j){
      int l = t + j * 256; int rr = l >> 3, c8 = l & 7;
      int cbase = cb * 64 + c8 * 8;
      u16x8 u = *(const u16x8*)(npw + (size_t)(rowbase + rr) * 4096 + cbase);
      f32x4 alo = *(const f32x4*)(AC + cbase);
      f32x4 ahi = *(const f32x4*)(AC + cbase + 4);
      f32x4 dlo = *(const f32x4*)(DC + cbase);
      f32x4 dhi = *(const f32x4*)(DC + cbase + 4);
      npt[rr][c8*8+0] = fmaxf(0.f, alo.x*bf(u[0]) + dlo.x);
      npt[rr][c8*8+1] = fmaxf(0.f, alo.y*bf(u[1]) + dlo.y);
      npt[rr][c8*8+2] = fmaxf(0.f, alo.z*bf(u[2]) + dlo.z);
      npt[rr][c8*8+3] = fmaxf(0.f, alo.w*bf(u[3]) + dlo.w);
      npt[rr][c8*8+4] = fmaxf(0.f, ahi.x*bf(u[4]) + dhi.x);
      npt[rr][c8*8+5] = fmaxf(0.f, ahi.y*bf(u[5]) + dhi.y);
      npt[rr][c8*8+6] = fmaxf(0.f, ahi.z*bf(u[6]) + dhi.z);
      npt[rr][c8*8+7] = fmaxf(0.f, ahi.w*bf(u[7]) + dhi.w);
    }
    #pragma unroll
    for (int j = 0; j < 2; ++j){
      int l = t + j * 256; int cc = l >> 3, o8 = l & 7;
      const float* src = lw + (size_t)(cb * 64 + cc) * 64 + o8 * 8;
      *(f32x4*)&lwt[cc][o8*8]     = *(const f32x4*)src;
      *(f32x4*)&lwt[cc][o8*8 + 4] = *(const f32x4*)(src + 4);
    }
    __syncthreads();
    #pragma unroll 8
    for (int cc = 0; cc < 64; ++cc){
      float x0 = npt[r0][cc], x1 = npt[r0+1][cc];
      f32x4 wA = *(const f32x4*)&lwt[cc][o0];
      f32x4 wB = *(const f32x4*)&lwt[cc][o0+4];
      accA += x0 * wA; accB += x0 * wB;
      accC += x1 * wA; accD += x1 * wB;
    }
  }
  f32x4 lbA = *(const f32x4*)(lb + o0);
  f32x4 lbB = *(const f32x4*)(lb + o0 + 4);
  accA += lbA; accB += lbB; accC += lbA; accD += lbB;
  float* dst0 = yw + (size_t)(rowbase + r0) * 64 + o0;
  *(f32x4*)dst0 = accA; *(f32x4*)(dst0 + 4) = accB;
  float* dst1 = yw + (size_t)(rowbase + r0 + 1) * 64 + o0;
  *(f32x4*)dst1 = accC; *(f32x4*)(dst1 + 4) = accD;
}

// ---------------- K8a: final-BN stats -> block partials ----------------
__global__ __launch_bounds__(256) void k_statL(const float* yw, float* PL){
  __shared__ float sh[4][128];
  int t = threadIdx.x;
  int o = t & 63;
  int w = t >> 6;
  int rg = blockIdx.x * 4 + w;
  float s = 0.f, q = 0.f;
  for (int r = rg * 64; r < rg * 64 + 64; ++r){
    float v = yw[(size_t)r * 64 + o];
    s += v; q += v*v;
  }
  sh[w][o] = s; sh[w][64+o] = q;
  __syncthreads();
  if (t < 128) PL[blockIdx.x*128 + t] = sh[0][t] + sh[1][t] + sh[2][t] + sh[3][t];
}

// ---------------- K8a2: reduce 64 blocks of PL -> SL ----------------
__global__ __launch_bounds__(128) void k_redL(const float* PL, float* SL){
  int t = threadIdx.x;
  float s = 0.f;
  for (int b = 0; b < 64; ++b) s += PL[b*128 + t];
  SL[t] = s;
}

// ---------------- K8b: final bn + relu + f32 store ----------------
__global__ __launch_bounds__(256) void k_final(const float* yw, const float* SL,
                                               const float* gl, const float* bl, float* out){
  int gid = blockIdx.x * 256 + threadIdx.x;  // < 16384*64
  int o = gid & 63;
  float m = SL[o] * (1.f/16384.f);
  float v = SL[64 + o] * (1.f/16384.f) - m*m;
  float a = gl[o] * rsqrtf(v + EPSF);
  float d = bl[o] - m*a;
  float y = fmaxf(0.f, a * yw[gid] + d);
  out[49152 + gid] = y;
}

extern "C" void kernel_launch(void* const* d_in, const int* in_sizes, int n_in,
                              void* d_out, int out_size, void* d_ws, size_t ws_size,
                              hipStream_t stream){
  (void)in_sizes; (void)n_in; (void)out_size; (void)ws_size;
  const float* xyz    = (const float*)d_in[0];
  const float* points = (const float*)d_in[1];
  const float* lc     = (const float*)d_in[2];
  const int*   nbrl   = (const int*)d_in[3];
  const int*   didx   = (const int*)d_in[4];
  const float* w0 = (const float*)d_in[5];
  const float* b0 = (const float*)d_in[6];
  const float* g0 = (const float*)d_in[7];
  const float* be0= (const float*)d_in[8];
  const float* w1 = (const float*)d_in[9];
  const float* b1 = (const float*)d_in[10];
  const float* g1 = (const float*)d_in[11];
  const float* be1= (const float*)d_in[12];
  const float* w2 = (const float*)d_in[13];
  const float* b2 = (const float*)d_in[14];
  const float* g2 = (const float*)d_in[15];
  const float* be2= (const float*)d_in[16];
  const float* gc = (const float*)d_in[17];
  const float* bc = (const float*)d_in[18];
  const float* lw = (const float*)d_in[19];
  const float* lb = (const float*)d_in[20];
  const float* gl = (const float*)d_in[21];
  const float* bl = (const float*)d_in[22];
  float* out = (float*)d_out;
  char* ws = (char*)d_ws;

  // float-offset layout in ws (small region):
  float* S0 = (float*)ws;            // 32     @0
  float* S1 = S0 + 32;               // 32     @32
  float* S2 = S1 + 32;               // 128    @64
  float* SL = S2 + 128;              // 128    @192
  float* AC = SL + 128;              // 4096   @320
  float* DC = AC + 4096;             // 4096   @4416
  float* P0 = DC + 4096;             // 8192   @8512
  float* P1 = P0 + 8192;             // 8192   @16704
  float* P2 = P1 + 8192;             // 32768  @24896
  float* PL = P2 + 32768;            // 8192   @57664
  float* slotC = PL + 8192;          // 16*8192=131072 @65856  (end 196928 floats = 787712 B)
  u16*  npw = (u16*)(ws + 1048576);                       // 128 MB bf16
  float* yw = (float*)(ws + 1048576 + 134217728);         // 4 MB f32

  hipMemsetAsync(slotC, 0, NSLOT * 8192 * sizeof(float), stream);  // only slotC needs zeroing
  k_newxyz <<<64,   256, 0, stream>>>(xyz, didx, out);
  k_wn0    <<<256,  256, 0, stream>>>(lc, w0, b0, P0);
  k_redP   <<<1,    256, 0, stream>>>(P0, S0, 32);
  k_wn1    <<<256,  256, 0, stream>>>(lc, w0, b0, g0, be0, S0, w1, b1, P1);
  k_redP   <<<1,    256, 0, stream>>>(P1, S1, 32);
  k_wn2    <<<256,  256, 0, stream>>>(lc, w0, b0, g0, be0, S0, w1, b1, g1, be1, S1, w2, b2, P2);
  k_redP   <<<1,    256, 0, stream>>>(P2, S2, 128);
  k_main   <<<1024, 256, 0, stream>>>(lc, nbrl, points, xyz,
                                      w0, b0, g0, be0, S0,
                                      w1, b1, g1, be1, S1,
                                      w2, b2, g2, be2, S2,
                                      npw, slotC);
  k_finC   <<<16,   256, 0, stream>>>(slotC, gc, bc, AC, DC);
  k_linear <<<256,  256, 0, stream>>>(npw, AC, DC, lw, lb, yw);
  k_statL  <<<64,   256, 0, stream>>>(yw, PL);
  k_redL   <<<1,    128, 0, stream>>>(PL, SL);
  k_final  <<<4096, 256, 0, stream>>>(yw, SL, gl, bl, out);
}

// Round 4
// 643.343 us; speedup vs baseline: 6.2166x; 3.1721x over previous
//
#include <hip/hip_runtime.h>

#define BB 16
#define NN 4096
#define NPOINTS 1024
#define KK 32
#define NPTS (BB*NPOINTS)        // 16384
#define NWN  (BB*NPOINTS*KK)     // 524288
#define EPSF 1e-5f
#define NSLOT 16

typedef unsigned short u16;
typedef u16  u16x8 __attribute__((ext_vector_type(8)));
typedef u16  u16x4 __attribute__((ext_vector_type(4)));
typedef float f32x4 __attribute__((ext_vector_type(4)));

__device__ __forceinline__ float bf(u16 u){
  union { unsigned int i; float f; } v; v.i = ((unsigned int)u) << 16; return v.f;
}
__device__ __forceinline__ u16 f2b(float f){
  union { float ff; unsigned int i; } v; v.ff = f;
  unsigned int r = v.i + 0x7FFFu + ((v.i >> 16) & 1u);
  return (u16)(r >> 16);
}
__device__ __forceinline__ void wave_red2(float& s, float& q){
  #pragma unroll
  for (int m = 1; m < 64; m <<= 1){ s += __shfl_xor(s, m); q += __shfl_xor(q, m); }
}

// ---------------- K0: new_xyz gather (f32 copy) ----------------
__global__ __launch_bounds__(256) void k_newxyz(const float* xyz, const int* didx, float* out){
  int p = blockIdx.x * 256 + threadIdx.x;
  if (p >= NPTS) return;
  int b = p >> 10;
  int idx = didx[p];
  const float* src = xyz + ((size_t)(b * NN + idx)) * 3;
  float* dst = out + (size_t)p * 3;
  dst[0] = src[0]; dst[1] = src[1]; dst[2] = src[2];
}

// ---------------- stats kernels: 256 blocks, partial write (no atomics) ----------------
__global__ __launch_bounds__(256) void k_wn0(const float* lc, const float* w0, const float* b0, float* P0){
  __shared__ float w0c[48], b0c[16];
  __shared__ float shs[4][16], shq[4][16];
  int t = threadIdx.x;
  if (t < 48) w0c[t] = w0[t];
  if (t < 16) b0c[t] = b0[t];
  __syncthreads();
  float s[16], q[16];
  #pragma unroll
  for (int oc = 0; oc < 16; ++oc){ s[oc] = 0.f; q[oc] = 0.f; }
  size_t base = (size_t)blockIdx.x * 2048 + t;
  for (int i = 0; i < 8; ++i){
    size_t p = base + (size_t)i * 256;
    float x0 = lc[p*3+0], x1 = lc[p*3+1], x2 = lc[p*3+2];
    #pragma unroll
    for (int oc = 0; oc < 16; ++oc){
      float y = w0c[oc*3]*x0 + w0c[oc*3+1]*x1 + w0c[oc*3+2]*x2 + b0c[oc];
      s[oc] += y; q[oc] += y*y;
    }
  }
  int lane = t & 63, wid = t >> 6;
  #pragma unroll
  for (int oc = 0; oc < 16; ++oc){
    wave_red2(s[oc], q[oc]);
    if (lane == 0){ shs[wid][oc] = s[oc]; shq[wid][oc] = q[oc]; }
  }
  __syncthreads();
  if (t < 16){
    P0[blockIdx.x*32 + t]      = shs[0][t] + shs[1][t] + shs[2][t] + shs[3][t];
    P0[blockIdx.x*32 + 16 + t] = shq[0][t] + shq[1][t] + shq[2][t] + shq[3][t];
  }
}

__global__ __launch_bounds__(256) void k_wn1(const float* lc, const float* w0, const float* b0,
                                             const float* g0, const float* be0, const float* S0,
                                             const float* w1, const float* b1, float* P1){
  __shared__ float w0c[48], b0c[16], a0[16], d0[16], w1c[256], b1c[16];
  __shared__ float shs[4][16], shq[4][16];
  int t = threadIdx.x;
  if (t < 48) w0c[t] = w0[t];
  if (t < 16){
    b0c[t] = b0[t]; b1c[t] = b1[t];
    float m = S0[t] * (1.0f/NWN);
    float v = S0[16+t] * (1.0f/NWN) - m*m;
    float a = g0[t] * rsqrtf(v + EPSF);
    a0[t] = a; d0[t] = be0[t] - m*a;
  }
  w1c[t] = w1[t];
  __syncthreads();
  float s[16], q[16];
  #pragma unroll
  for (int oc = 0; oc < 16; ++oc){ s[oc] = 0.f; q[oc] = 0.f; }
  size_t base = (size_t)blockIdx.x * 2048 + t;
  for (int i = 0; i < 8; ++i){
    size_t p = base + (size_t)i * 256;
    float x0 = lc[p*3+0], x1 = lc[p*3+1], x2 = lc[p*3+2];
    float h0[16];
    #pragma unroll
    for (int oc = 0; oc < 16; ++oc){
      float y = w0c[oc*3]*x0 + w0c[oc*3+1]*x1 + w0c[oc*3+2]*x2 + b0c[oc];
      h0[oc] = fmaxf(0.f, a0[oc]*y + d0[oc]);
    }
    #pragma unroll
    for (int oc = 0; oc < 16; ++oc){
      float y = b1c[oc];
      #pragma unroll
      for (int ic = 0; ic < 16; ++ic) y += w1c[oc*16+ic]*h0[ic];
      s[oc] += y; q[oc] += y*y;
    }
  }
  int lane = t & 63, wid = t >> 6;
  #pragma unroll
  for (int oc = 0; oc < 16; ++oc){
    wave_red2(s[oc], q[oc]);
    if (lane == 0){ shs[wid][oc] = s[oc]; shq[wid][oc] = q[oc]; }
  }
  __syncthreads();
  if (t < 16){
    P1[blockIdx.x*32 + t]      = shs[0][t] + shs[1][t] + shs[2][t] + shs[3][t];
    P1[blockIdx.x*32 + 16 + t] = shq[0][t] + shq[1][t] + shq[2][t] + shq[3][t];
  }
}

// k_wn2 restructured: chunked-LDS h0/h1, one layer2 channel per thread (2 accumulators).
// Fixes round-3 spill: VGPR 256 -> ~40, scratch traffic -> 0.
__global__ __launch_bounds__(256) void k_wn2(const float* lc,
    const float* w0, const float* b0, const float* g0, const float* be0, const float* S0,
    const float* w1, const float* b1, const float* g1, const float* be1, const float* S1,
    const float* w2, const float* b2, float* P2){
  __shared__ float w0c[48], b0c[16], a0[16], d0[16];
  __shared__ float w1c[256], b1c[16], a1[16], d1[16];
  __shared__ float w2c[64][17], b2c[64];
  __shared__ float h0s[64][17], h1s[64][17];
  __shared__ float shs[4][64], shq[4][64];
  int t = threadIdx.x;
  if (t < 48) w0c[t] = w0[t];
  if (t < 16){
    b0c[t] = b0[t]; b1c[t] = b1[t];
    float m = S0[t] * (1.0f/NWN);
    float v = S0[16+t] * (1.0f/NWN) - m*m;
    float a = g0[t] * rsqrtf(v + EPSF);
    a0[t] = a; d0[t] = be0[t] - m*a;
    float m1 = S1[t] * (1.0f/NWN);
    float v1 = S1[16+t] * (1.0f/NWN) - m1*m1;
    float aa = g1[t] * rsqrtf(v1 + EPSF);
    a1[t] = aa; d1[t] = be1[t] - m1*aa;
  }
  w1c[t] = w1[t];
  for (int i = t; i < 1024; i += 256) w2c[i>>4][i&15] = w2[i];
  if (t < 64) b2c[t] = b2[t];
  __syncthreads();
  int oc = t & 63, w = t >> 6;
  float s = 0.f, q = 0.f;
  size_t cbase = (size_t)blockIdx.x * 2048;
  for (int ch = 0; ch < 32; ++ch){
    size_t pbase = cbase + ch * 64;
    __syncthreads();   // prev stage-3 reads of h1s done; h0s safe (barrier after its last read)
    #pragma unroll
    for (int j = 0; j < 4; ++j){
      int l = t + j * 256;           // 0..1023
      int k = l >> 4, c = l & 15;
      const float* xp = lc + (pbase + k) * 3;
      float y = w0c[c*3]*xp[0] + w0c[c*3+1]*xp[1] + w0c[c*3+2]*xp[2] + b0c[c];
      h0s[k][c] = fmaxf(0.f, a0[c]*y + d0[c]);
    }
    __syncthreads();
    #pragma unroll
    for (int j = 0; j < 4; ++j){
      int l = t + j * 256;
      int k = l >> 4, c = l & 15;
      float y = b1c[c];
      #pragma unroll
      for (int ic = 0; ic < 16; ++ic) y += w1c[c*16+ic] * h0s[k][ic];
      h1s[k][c] = fmaxf(0.f, a1[c]*y + d1[c]);
    }
    __syncthreads();
    #pragma unroll
    for (int kk = 0; kk < 16; ++kk){
      int k = w * 16 + kk;
      float y = b2c[oc];
      #pragma unroll
      for (int ic = 0; ic < 16; ++ic) y += w2c[oc][ic] * h1s[k][ic];
      s += y; q += y*y;
    }
  }
  shs[w][oc] = s; shq[w][oc] = q;
  __syncthreads();
  if (t < 64){
    P2[blockIdx.x*128 + t]      = shs[0][t] + shs[1][t] + shs[2][t] + shs[3][t];
    P2[blockIdx.x*128 + 64 + t] = shq[0][t] + shq[1][t] + shq[2][t] + shq[3][t];
  }
}

// ---------------- generic partial reduce: S[c] = sum over 256 rows of P[r*nch + c] ----------------
__global__ __launch_bounds__(256) void k_redP(const float* P, float* S, int nch){
  int t = threadIdx.x;
  if (t >= nch) return;
  float s = 0.f;
  for (int r = 0; r < 256; ++r) s += P[r*nch + t];
  S[t] = s;
}

// ---------------- K5: main pass — gather + WeightNet + per-point 64x32x64 matmul ----------------
__global__ __launch_bounds__(256) void k_main(const float* lcg, const int* nbrg,
    const float* points, const float* xyz,
    const float* w0, const float* b0, const float* g0, const float* be0, const float* S0,
    const float* w1, const float* b1, const float* g1, const float* be1, const float* S1,
    const float* w2, const float* b2, const float* g2, const float* be2, const float* S2,
    u16* npw, float* slotC){
  __shared__ float G[32][64];
  __shared__ float W[32][64];
  __shared__ float H0[32][16];
  __shared__ float H1[32][16];
  __shared__ float lcs[32][4];
  __shared__ int   nbr[32];
  __shared__ float w0c[48], b0c[16], a0c[16], d0c[16];
  __shared__ float w1c[16][17], b1c[16], a1c[16], d1c[16];
  __shared__ float w2c[64][17], b2c[64], a2c[64], d2c[64];
  int t = threadIdx.x;
  if (t < 48) w0c[t] = w0[t];
  if (t < 16){
    b0c[t] = b0[t]; b1c[t] = b1[t];
    float m = S0[t] * (1.0f/NWN);
    float v = S0[16+t] * (1.0f/NWN) - m*m;
    float a = g0[t] * rsqrtf(v + EPSF);
    a0c[t] = a; d0c[t] = be0[t] - m*a;
    float m1 = S1[t] * (1.0f/NWN);
    float v1 = S1[16+t] * (1.0f/NWN) - m1*m1;
    float aa = g1[t] * rsqrtf(v1 + EPSF);
    a1c[t] = aa; d1c[t] = be1[t] - m1*aa;
  }
  w1c[t>>4][t&15] = w1[t];
  for (int i = t; i < 1024; i += 256) w2c[i>>4][i&15] = w2[i];
  if (t < 64){
    b2c[t] = b2[t];
    float m = S2[t] * (1.0f/NWN);
    float v = S2[64+t] * (1.0f/NWN) - m*m;
    float a = g2[t] * rsqrtf(v + EPSF);
    a2c[t] = a; d2c[t] = be2[t] - m*a;
  }
  int ti = t & 15, to = t >> 4;
  int i0 = ti * 4, o0 = to * 4;
  f32x4 cs0 = {0,0,0,0}, cs1 = cs0, cs2 = cs0, cs3 = cs0;
  f32x4 cq0 = cs0, cq1 = cs0, cq2 = cs0, cq3 = cs0;
  for (int p = 0; p < 16; ++p){
    int point = blockIdx.x * 16 + p;
    int b = point >> 10;
    __syncthreads();  // previous matmul done before overwriting LDS
    if (t < 32) nbr[t] = nbrg[(size_t)point * 32 + t];
    if (t < 96){ int k = t / 3, c = t % 3; lcs[k][c] = lcg[(size_t)point * 96 + t]; }
    __syncthreads();
    // gather grouped [32 nbr][64 ch] directly from points/xyz
    {
      int k = t >> 3, c8 = t & 7;
      int n = nbr[k];
      const float* prow = points + (size_t)(b * NN + n) * 61;
      const float* xr   = xyz    + (size_t)(b * NN + n) * 3;
      #pragma unroll
      for (int j = 0; j < 8; ++j){
        int c = c8 * 8 + j;
        G[k][c] = (c < 61) ? prow[c] : xr[c - 61];
      }
    }
    #pragma unroll
    for (int j = 0; j < 2; ++j){
      int l = t + j * 256; int k = l >> 4, oc = l & 15;
      float y = w0c[oc*3]*lcs[k][0] + w0c[oc*3+1]*lcs[k][1] + w0c[oc*3+2]*lcs[k][2] + b0c[oc];
      H0[k][oc] = fmaxf(0.f, a0c[oc]*y + d0c[oc]);
    }
    __syncthreads();
    #pragma unroll
    for (int j = 0; j < 2; ++j){
      int l = t + j * 256; int k = l >> 4, oc = l & 15;
      float y = b1c[oc];
      #pragma unroll
      for (int ic = 0; ic < 16; ++ic) y += w1c[oc][ic] * H0[k][ic];
      H1[k][oc] = fmaxf(0.f, a1c[oc]*y + d1c[oc]);
    }
    __syncthreads();
    {
      int oo = t & 63;
      #pragma unroll
      for (int e = 0; e < 8; ++e){
        int k = (t >> 6) + e * 4;
        float y = b2c[oo];
        #pragma unroll
        for (int ic = 0; ic < 16; ++ic) y += w2c[oo][ic] * H1[k][ic];
        W[k][oo] = fmaxf(0.f, a2c[oo]*y + d2c[oo]);
      }
    }
    __syncthreads();
    // matmul: np[i][o] = sum_k G[k][i]*W[k][o], 4x4 register tile
    f32x4 acc0 = {0,0,0,0}, acc1 = acc0, acc2 = acc0, acc3 = acc0;
    #pragma unroll
    for (int k = 0; k < 32; ++k){
      f32x4 g = *(const f32x4*)&G[k][i0];
      f32x4 w = *(const f32x4*)&W[k][o0];
      acc0 += g.x * w; acc1 += g.y * w; acc2 += g.z * w; acc3 += g.w * w;
    }
    size_t rowb = (size_t)point * 4096 + o0;
    u16x4 u;
    u[0]=f2b(acc0.x); u[1]=f2b(acc0.y); u[2]=f2b(acc0.z); u[3]=f2b(acc0.w);
    *(u16x4*)(npw + rowb + (size_t)(i0+0)*64) = u;
    u[0]=f2b(acc1.x); u[1]=f2b(acc1.y); u[2]=f2b(acc1.z); u[3]=f2b(acc1.w);
    *(u16x4*)(npw + rowb + (size_t)(i0+1)*64) = u;
    u[0]=f2b(acc2.x); u[1]=f2b(acc2.y); u[2]=f2b(acc2.z); u[3]=f2b(acc2.w);
    *(u16x4*)(npw + rowb + (size_t)(i0+2)*64) = u;
    u[0]=f2b(acc3.x); u[1]=f2b(acc3.y); u[2]=f2b(acc3.z); u[3]=f2b(acc3.w);
    *(u16x4*)(npw + rowb + (size_t)(i0+3)*64) = u;
    cs0 += acc0; cq0 += acc0*acc0;
    cs1 += acc1; cq1 += acc1*acc1;
    cs2 += acc2; cq2 += acc2*acc2;
    cs3 += acc3; cq3 += acc3*acc3;
  }
  // channel sums -> one of NSLOT slot copies (cuts same-address chains NSLOT-fold)
  float* slot = slotC + (size_t)(blockIdx.x & (NSLOT-1)) * 8192;
  int ch0 = i0 * 64 + o0;
  #pragma unroll
  for (int dj = 0; dj < 4; ++dj){
    atomicAdd(&slot[ch0 +   0 + dj], cs0[dj]); atomicAdd(&slot[4096 + ch0 +   0 + dj], cq0[dj]);
    atomicAdd(&slot[ch0 +  64 + dj], cs1[dj]); atomicAdd(&slot[4096 + ch0 +  64 + dj], cq1[dj]);
    atomicAdd(&slot[ch0 + 128 + dj], cs2[dj]); atomicAdd(&slot[4096 + ch0 + 128 + dj], cq2[dj]);
    atomicAdd(&slot[ch0 + 192 + dj], cs3[dj]); atomicAdd(&slot[4096 + ch0 + 192 + dj], cq3[dj]);
  }
}

// ---------------- K6b: reduce slots + finalize 4096-channel BN scale/shift ----------------
__global__ __launch_bounds__(256) void k_finC(const float* slotC, const float* gc, const float* bc,
                                              float* AC, float* DC){
  int ch = blockIdx.x * 256 + threadIdx.x;
  float s = 0.f, q = 0.f;
  #pragma unroll
  for (int sl = 0; sl < NSLOT; ++sl){
    s += slotC[(size_t)sl * 8192 + ch];
    q += slotC[(size_t)sl * 8192 + 4096 + ch];
  }
  float m = s * (1.f/16384.f);
  float v = q * (1.f/16384.f) - m*m;
  float a = gc[ch] * rsqrtf(v + EPSF);
  AC[ch] = a; DC[ch] = bc[ch] - m*a;
}

// ---------------- K7: [16384,4096] x [4096,64] with fused bn+relu on A ----------------
__global__ __launch_bounds__(256) void k_linear(const u16* npw, const float* AC, const float* DC,
                                                const float* lw, const float* lb, float* yw){
  __shared__ float npt[64][65];
  __shared__ float lwt[64][64];
  int t = threadIdx.x;
  int rowbase = blockIdx.x * 64;
  int r0 = (t & 31) * 2;
  int o0 = (t >> 5) * 8;
  f32x4 accA = {0,0,0,0}, accB = accA, accC = accA, accD = accA;
  for (int cb = 0; cb < 64; ++cb){
    __syncthreads();
    #pragma unroll
    for (int j = 0; j < 2; ++j){
      int l = t + j * 256; int rr = l >> 3, c8 = l & 7;
      int cbase = cb * 64 + c8 * 8;
      u16x8 u = *(const u16x8*)(npw + (size_t)(rowbase + rr) * 4096 + cbase);
      f32x4 alo = *(const f32x4*)(AC + cbase);
      f32x4 ahi = *(const f32x4*)(AC + cbase + 4);
      f32x4 dlo = *(const f32x4*)(DC + cbase);
      f32x4 dhi = *(const f32x4*)(DC + cbase + 4);
      npt[rr][c8*8+0] = fmaxf(0.f, alo.x*bf(u[0]) + dlo.x);
      npt[rr][c8*8+1] = fmaxf(0.f, alo.y*bf(u[1]) + dlo.y);
      npt[rr][c8*8+2] = fmaxf(0.f, alo.z*bf(u[2]) + dlo.z);
      npt[rr][c8*8+3] = fmaxf(0.f, alo.w*bf(u[3]) + dlo.w);
      npt[rr][c8*8+4] = fmaxf(0.f, ahi.x*bf(u[4]) + dhi.x);
      npt[rr][c8*8+5] = fmaxf(0.f, ahi.y*bf(u[5]) + dhi.y);
      npt[rr][c8*8+6] = fmaxf(0.f, ahi.z*bf(u[6]) + dhi.z);
      npt[rr][c8*8+7] = fmaxf(0.f, ahi.w*bf(u[7]) + dhi.w);
    }
    #pragma unroll
    for (int j = 0; j < 2; ++j){
      int l = t + j * 256; int cc = l >> 3, o8 = l & 7;
      const float* src = lw + (size_t)(cb * 64 + cc) * 64 + o8 * 8;
      *(f32x4*)&lwt[cc][o8*8]     = *(const f32x4*)src;
      *(f32x4*)&lwt[cc][o8*8 + 4] = *(const f32x4*)(src + 4);
    }
    __syncthreads();
    #pragma unroll 8
    for (int cc = 0; cc < 64; ++cc){
      float x0 = npt[r0][cc], x1 = npt[r0+1][cc];
      f32x4 wA = *(const f32x4*)&lwt[cc][o0];
      f32x4 wB = *(const f32x4*)&lwt[cc][o0+4];
      accA += x0 * wA; accB += x0 * wB;
      accC += x1 * wA; accD += x1 * wB;
    }
  }
  f32x4 lbA = *(const f32x4*)(lb + o0);
  f32x4 lbB = *(const f32x4*)(lb + o0 + 4);
  accA += lbA; accB += lbB; accC += lbA; accD += lbB;
  float* dst0 = yw + (size_t)(rowbase + r0) * 64 + o0;
  *(f32x4*)dst0 = accA; *(f32x4*)(dst0 + 4) = accB;
  float* dst1 = yw + (size_t)(rowbase + r0 + 1) * 64 + o0;
  *(f32x4*)dst1 = accC; *(f32x4*)(dst1 + 4) = accD;
}

// ---------------- K8a: final-BN stats -> block partials ----------------
__global__ __launch_bounds__(256) void k_statL(const float* yw, float* PL){
  __shared__ float sh[4][128];
  int t = threadIdx.x;
  int o = t & 63;
  int w = t >> 6;
  int rg = blockIdx.x * 4 + w;
  float s = 0.f, q = 0.f;
  for (int r = rg * 64; r < rg * 64 + 64; ++r){
    float v = yw[(size_t)r * 64 + o];
    s += v; q += v*v;
  }
  sh[w][o] = s; sh[w][64+o] = q;
  __syncthreads();
  if (t < 128) PL[blockIdx.x*128 + t] = sh[0][t] + sh[1][t] + sh[2][t] + sh[3][t];
}

// ---------------- K8a2: reduce 64 blocks of PL -> SL ----------------
__global__ __launch_bounds__(128) void k_redL(const float* PL, float* SL){
  int t = threadIdx.x;
  float s = 0.f;
  for (int b = 0; b < 64; ++b) s += PL[b*128 + t];
  SL[t] = s;
}

// ---------------- K8b: final bn + relu + f32 store ----------------
__global__ __launch_bounds__(256) void k_final(const float* yw, const float* SL,
                                               const float* gl, const float* bl, float* out){
  int gid = blockIdx.x * 256 + threadIdx.x;  // < 16384*64
  int o = gid & 63;
  float m = SL[o] * (1.f/16384.f);
  float v = SL[64 + o] * (1.f/16384.f) - m*m;
  float a = gl[o] * rsqrtf(v + EPSF);
  float d = bl[o] - m*a;
  float y = fmaxf(0.f, a * yw[gid] + d);
  out[49152 + gid] = y;
}

extern "C" void kernel_launch(void* const* d_in, const int* in_sizes, int n_in,
                              void* d_out, int out_size, void* d_ws, size_t ws_size,
                              hipStream_t stream){
  (void)in_sizes; (void)n_in; (void)out_size; (void)ws_size;
  const float* xyz    = (const float*)d_in[0];
  const float* points = (const float*)d_in[1];
  const float* lc     = (const float*)d_in[2];
  const int*   nbrl   = (const int*)d_in[3];
  const int*   didx   = (const int*)d_in[4];
  const float* w0 = (const float*)d_in[5];
  const float* b0 = (const float*)d_in[6];
  const float* g0 = (const float*)d_in[7];
  const float* be0= (const float*)d_in[8];
  const float* w1 = (const float*)d_in[9];
  const float* b1 = (const float*)d_in[10];
  const float* g1 = (const float*)d_in[11];
  const float* be1= (const float*)d_in[12];
  const float* w2 = (const float*)d_in[13];
  const float* b2 = (const float*)d_in[14];
  const float* g2 = (const float*)d_in[15];
  const float* be2= (const float*)d_in[16];
  const float* gc = (const float*)d_in[17];
  const float* bc = (const float*)d_in[18];
  const float* lw = (const float*)d_in[19];
  const float* lb = (const float*)d_in[20];
  const float* gl = (const float*)d_in[21];
  const float* bl = (const float*)d_in[22];
  float* out = (float*)d_out;
  char* ws = (char*)d_ws;

  // float-offset layout in ws (small region):
  float* S0 = (float*)ws;            // 32     @0
  float* S1 = S0 + 32;               // 32     @32
  float* S2 = S1 + 32;               // 128    @64
  float* SL = S2 + 128;              // 128    @192
  float* AC = SL + 128;              // 4096   @320
  float* DC = AC + 4096;             // 4096   @4416
  float* P0 = DC + 4096;             // 8192   @8512
  float* P1 = P0 + 8192;             // 8192   @16704
  float* P2 = P1 + 8192;             // 32768  @24896
  float* PL = P2 + 32768;            // 8192   @57664
  float* slotC = PL + 8192;          // 16*8192=131072 @65856  (end 196928 floats = 787712 B)
  u16*  npw = (u16*)(ws + 1048576);                       // 128 MB bf16
  float* yw = (float*)(ws + 1048576 + 134217728);         // 4 MB f32

  hipMemsetAsync(slotC, 0, NSLOT * 8192 * sizeof(float), stream);  // only slotC needs zeroing
  k_newxyz <<<64,   256, 0, stream>>>(xyz, didx, out);
  k_wn0    <<<256,  256, 0, stream>>>(lc, w0, b0, P0);
  k_redP   <<<1,    256, 0, stream>>>(P0, S0, 32);
  k_wn1    <<<256,  256, 0, stream>>>(lc, w0, b0, g0, be0, S0, w1, b1, P1);
  k_redP   <<<1,    256, 0, stream>>>(P1, S1, 32);
  k_wn2    <<<256,  256, 0, stream>>>(lc, w0, b0, g0, be0, S0, w1, b1, g1, be1, S1, w2, b2, P2);
  k_redP   <<<1,    256, 0, stream>>>(P2, S2, 128);
  k_main   <<<1024, 256, 0, stream>>>(lc, nbrl, points, xyz,
                                      w0, b0, g0, be0, S0,
                                      w1, b1, g1, be1, S1,
                                      w2, b2, g2, be2, S2,
                                      npw, slotC);
  k_finC   <<<16,   256, 0, stream>>>(slotC, gc, bc, AC, DC);
  k_linear <<<256,  256, 0, stream>>>(npw, AC, DC, lw, lb, yw);
  k_statL  <<<64,   256, 0, stream>>>(yw, PL);
  k_redL   <<<1,    128, 0, stream>>>(PL, SL);
  k_final  <<<4096, 256, 0, stream>>>(yw, SL, gl, bl, out);
}